// Round 17
// baseline (145.728 us; speedup 1.0000x reference)
//
#include <hip/hip_runtime.h>
#include <hip/hip_bf16.h>
#include <cstdint>

#define EL 1048576ull   // 1Mi elements

typedef __bf16 bf16_t;
typedef bf16_t bf16x8 __attribute__((ext_vector_type(8)));
typedef float  f32x4  __attribute__((ext_vector_type(4)));
typedef unsigned int u32x2 __attribute__((ext_vector_type(2)));
typedef unsigned int u32x4 __attribute__((ext_vector_type(4)));

__device__ __forceinline__ unsigned short f2bf(float f) {
  unsigned int u = __builtin_bit_cast(unsigned int, f);
  u += 0x7FFFu + ((u >> 16) & 1u);   // RNE
  return (unsigned short)(u >> 16);
}

// pack 2 f32 -> 2 bf16 in one u32 (lo -> low half), RNE; proven round 5
__device__ __forceinline__ unsigned int cvtpk(float lo, float hi2) {
  unsigned int r;
  asm("v_cvt_pk_bf16_f32 %0, %1, %2" : "=v"(r) : "v"(lo), "v"(hi2));
  return r;
}

__device__ __forceinline__ float fexp2(float x) {
#if __has_builtin(__builtin_amdgcn_exp2f)
  return __builtin_amdgcn_exp2f(x);
#else
  return exp2f(x);
#endif
}

typedef __attribute__((address_space(1))) void as1_void;
typedef __attribute__((address_space(3))) void as3_void;
__device__ __forceinline__ void load_lds16(const void* g, void* l) {
  __builtin_amdgcn_global_load_lds((as1_void*)g, (as3_void*)l, 16, 0, 0);
}

// P repack via permlane swaps (VALU, no LDS pipe); proven round 6
__device__ __forceinline__ bf16x8 repack_af(const f32x4 s0v, const f32x4 s1v) {
  unsigned int c00 = cvtpk(s0v[0], s0v[1]);
  unsigned int c01 = cvtpk(s0v[2], s0v[3]);
  unsigned int c10 = cvtpk(s1v[0], s1v[1]);
  unsigned int c11 = cvtpk(s1v[2], s1v[3]);
  asm("v_permlane32_swap_b32 %0, %1" : "+v"(c00), "+v"(c10));
  asm("v_permlane16_swap_b32 %0, %1" : "+v"(c00), "+v"(c10));
  asm("v_permlane32_swap_b32 %0, %1" : "+v"(c01), "+v"(c11));
  asm("v_permlane16_swap_b32 %0, %1" : "+v"(c01), "+v"(c11));
  u32x4 wd; wd[0] = c00; wd[1] = c01; wd[2] = c10; wd[3] = c11;
  return __builtin_bit_cast(bf16x8, wd);
}

// ---------------------------------------------------------------- convert
__global__ __launch_bounds__(256) void convert_all(
    const float* __restrict__ q, const float* __restrict__ k, const float* __restrict__ v,
    const float* __restrict__ wq, const float* __restrict__ wk,
    const float* __restrict__ wv, const float* __restrict__ wo,
    unsigned short* __restrict__ ws)
{
  const size_t total_v4 = 4 * EL; // 16M elems / 4
  for (size_t v4 = (size_t)blockIdx.x * blockDim.x + threadIdx.x; v4 < total_v4;
       v4 += (size_t)gridDim.x * blockDim.x) {
    size_t e = v4 * 4;
    unsigned seg = (unsigned)(e >> 20);
    const float* s; size_t base;
    if      (seg < 4)   { s = q;  base = 0; }
    else if (seg < 8)   { s = k;  base = 4*EL; }
    else if (seg < 12)  { s = v;  base = 8*EL; }
    else if (seg == 12) { s = wq; base = 12*EL; }
    else if (seg == 13) { s = wk; base = 13*EL; }
    else if (seg == 14) { s = wv; base = 14*EL; }
    else                { s = wo; base = 15*EL; }
    const float4 f = *(const float4*)(s + (e - base));
    ushort4 o;
    o.x = f2bf(f.x); o.y = f2bf(f.y); o.z = f2bf(f.z); o.w = f2bf(f.w);
    *(ushort4*)(ws + e) = o;
  }
}

// ---------------------------------------------------------------- GEMM main loop (acc += A * B^T)
template <int BM, int BN, int WM, int WN>
__device__ __forceinline__ void gemm_bt_main(
    const unsigned short* __restrict__ A,
    const unsigned short* __restrict__ B,
    f32x4 (&acc)[BM / WM / 16][BN / WN / 16],
    const int tm, const int tn)
{
  constexpr int K = 1024, BK = 64;
  constexpr int AM = BM / WM / 16, AN = BN / WN / 16;
  __shared__ __align__(16) unsigned short sA[BM * BK];
  __shared__ __align__(16) unsigned short sB[BN * BK];
  const int tid  = threadIdx.x;
  const int wave = tid >> 6, lane = tid & 63;
  const int wm = wave / WN, wn = wave % WN;
  const int l16 = lane & 15, hi = lane >> 4, swz = l16 & 7;

  for (int k0 = 0; k0 < K; k0 += BK) {
    __syncthreads();
#pragma unroll
    for (int i = 0; i < BM * 8 / 256; i++) {
      int p = i * 256 + tid;
      int row = p >> 3, c = p & 7;
      load_lds16(A + (size_t)(tm + row) * K + k0 + ((c ^ (row & 7)) * 8),
                 &sA[(i * 256 + wave * 64) * 8]);
    }
#pragma unroll
    for (int i = 0; i < BN * 8 / 256; i++) {
      int p = i * 256 + tid;
      int row = p >> 3, c = p & 7;
      load_lds16(B + (size_t)(tn + row) * K + k0 + ((c ^ (row & 7)) * 8),
                 &sB[(i * 256 + wave * 64) * 8]);
    }
    __syncthreads();

#pragma unroll
    for (int kk = 0; kk < 2; kk++) {
      bf16x8 af[AM], bfr[AN];
#pragma unroll
      for (int i = 0; i < AM; i++) {
        int row = wm * (BM / WM) + i * 16 + l16;
        af[i] = *(const bf16x8*)&sA[row * BK + (((kk * 4 + hi) ^ swz) * 8)];
      }
#pragma unroll
      for (int j = 0; j < AN; j++) {
        int row = wn * (BN / WN) + j * 16 + l16;
        bfr[j] = *(const bf16x8*)&sB[row * BK + (((kk * 4 + hi) ^ swz) * 8)];
      }
#pragma unroll
      for (int i = 0; i < AM; i++)
#pragma unroll
        for (int j = 0; j < AN; j++)
          acc[i][j] = __builtin_amdgcn_mfma_f32_16x16x32_bf16(af[i], bfr[j], acc[i][j], 0, 0, 0);
    }
  }
}

// ---------------------------------------------------------------- QKV projections
// Grid (8, 32, 3). XCD = blockIdx.x. A-panel's 8 sharers pinned to one XCD.
__global__ __launch_bounds__(256, 3) void qkv_gemm(
    const unsigned short* qb, const unsigned short* kb, const unsigned short* vb,
    const unsigned short* wqb, const unsigned short* wkb, const unsigned short* wvb,
    const float* bq, const float* bk, const float* bv,
    unsigned short* Qp, unsigned short* Kp, unsigned short* Vt)
{
  const unsigned short* A; const unsigned short* B; const float* bias;
  if (blockIdx.z == 0)      { A = qb; B = wqb; bias = bq; }
  else if (blockIdx.z == 1) { A = kb; B = wkb; bias = bk; }
  else                      { A = vb; B = wvb; bias = bv; }

  const int xd = blockIdx.x, yd = blockIdx.y;
  const int mt = xd + 8 * (yd & 3);    // A-panel id 0..31, pinned to XCD xd
  const int nt = yd >> 2;              // 0..7
  const int tm = mt * 128, tn = nt * 128;

  f32x4 acc[4][4] = {};
  gemm_bt_main<128, 128, 2, 2>(A, B, acc, tm, tn);

  const int tid = threadIdx.x, wave = tid >> 6, lane = tid & 63;
  const int wm = wave >> 1, wn = wave & 1;
  const int l16 = lane & 15, hi = lane >> 4;

  if (blockIdx.z < 2) {
    unsigned short* C = (blockIdx.z == 0) ? Qp : Kp;
    const float scale = (blockIdx.z == 0) ? 0.18033688011112042f : 1.0f; // 0.125*log2(e)
#pragma unroll
    for (int i = 0; i < 4; i++) {
      int row0 = tm + wm * 64 + i * 16 + hi * 4;
#pragma unroll
      for (int j = 0; j < 4; j++) {
        int col = tn + wn * 64 + j * 16 + l16;
        float bv2 = bias[col];
#pragma unroll
        for (int r = 0; r < 4; r++)
          C[(size_t)(row0 + r) * 1024 + col] = f2bf((acc[i][j][r] + bv2) * scale);
      }
    }
  } else {
    // transposed V write: lane's 4 rows are 4 consecutive s -> one 8B store
#pragma unroll
    for (int i = 0; i < 4; i++) {
      int row0 = tm + wm * 64 + i * 16 + hi * 4;
      int bb = row0 >> 11, s = row0 & 2047;
#pragma unroll
      for (int j = 0; j < 4; j++) {
        int col = tn + wn * 64 + j * 16 + l16;
        int hh = col >> 6, d = col & 63;
        float bv2 = bias[col];
        u32x2 w;
        w[0] = cvtpk(acc[i][j][0] + bv2, acc[i][j][1] + bv2);
        w[1] = cvtpk(acc[i][j][2] + bv2, acc[i][j][3] + bv2);
        *(u32x2*)&Vt[((size_t)(bb * 16 + hh) * 64 + d) * 2048 + s] = w;
      }
    }
  }
}

// Grid (16, 32). XCD = x%8. Pin each Yb A-panel's 16 sharers to one XCD.
__global__ __launch_bounds__(256, 2) void out_gemm(
    const unsigned short* Yb, const unsigned short* wob, const float* bo, float* out)
{
  const int xd = blockIdx.x, yd = blockIdx.y;
  const int mt = (xd & 7) + 8 * (yd & 3);   // 0..31, pinned to XCD xd&7
  const int nt = (xd >> 3) + 2 * (yd >> 2); // 0..15
  const int tm = mt * 128, tn = nt * 64;

  f32x4 acc[2][4] = {};
  gemm_bt_main<128, 64, 4, 1>(Yb, wob, acc, tm, tn);

  const int tid = threadIdx.x, wave = tid >> 6, lane = tid & 63;
  const int l16 = lane & 15, hi = lane >> 4;
#pragma unroll
  for (int i = 0; i < 2; i++) {
    int row0 = tm + wave * 32 + i * 16 + hi * 4;
#pragma unroll
    for (int j = 0; j < 4; j++) {
      int col = tn + j * 16 + l16;
      float bv2 = bo[col];
#pragma unroll
      for (int r = 0; r < 4; r++)
        out[(size_t)(row0 + r) * 1024 + col] = acc[i][j][r] + bv2;
    }
  }
}

// ---------------------------------------------------------------- flash attention
// IN-BLOCK KV-SPLIT, KVBLK=32, 32KB LDS -> 3 blocks/CU (6 waves/SIMD).
// 8 waves x 32 q-rows; waves 0-3 kv[0,1024), waves 4-7 kv[1024,2048), same 128 q.
// Single-barrier pipeline per tile. Constant-max softmax (exp2(s-16), shift baked
// into hoisted MFMA C-operand). Q prologue staged across the four idle buf-1
// regions. Halves combine via 2-pass LDS epilogue (sO[64][66] fits 32KB).
__global__ __launch_bounds__(512, 6) void attn_kernel(
    const unsigned short* __restrict__ Qp, const unsigned short* __restrict__ Kp,
    const unsigned short* __restrict__ Vt, const int* __restrict__ mask,
    unsigned short* __restrict__ Yb)
{
  constexpr int S = 2048, H = 1024;
  __shared__ __align__(16) unsigned short smem[16384];   // 32KB
  // shorts layout: K: h0b0[0,2048) h0b1[2048,4096) h1b0[4096,6144) h1b1[6144,8192)
  //                V: 8192 + same. Q prologue -> the four buf-1 regions (2048+w4*4096).

  const int tid = threadIdx.x, wave = tid >> 6, lane = tid & 63;
  const int l16 = lane & 15, hi = lane >> 4, swz = l16 & 7;
  const int half = wave >> 2, w4 = wave & 3;
  const int kvoff = half * 1024;
  const int xd = blockIdx.x, hd = blockIdx.y;
  const int h  = (xd & 7) + 8 * (hd & 1);            // pinned to XCD xd&7
  const int qt = ((xd >> 3) + 2 * (hd >> 1)) * 128;  // 0..15 q-tile
  const int b = blockIdx.z, bh = b * 16 + h;
  const unsigned short* Qb = Qp + (size_t)b * S * H + (size_t)h * 64;
  const unsigned short* Kb = Kp + (size_t)b * S * H + (size_t)h * 64;
  const unsigned short* Vb = Vt + (size_t)bh * 64 * 2048;

  unsigned short* sK0 = smem + half * 4096;
  unsigned short* sK1 = sK0 + 2048;
  unsigned short* sV0 = smem + 8192 + half * 4096;
  unsigned short* sV1 = sV0 + 2048;

  // loop-invariant LDS read offsets (shorts)
  const int kinv0 = l16 * 64 + ((hi ^ swz) * 8);               // K row stride 64
  const int kinv1 = l16 * 64 + (((4 + hi) ^ swz) * 8);
  const int vinv  = l16 * 32 + ((hi ^ ((l16 >> 1) & 3)) * 8);  // V row stride 32

  // ---- stage Q (128x64 = 16KB) into the four idle buf-1 regions
#pragma unroll
  for (int i = 0; i < 2; i++) {
    const int g0 = i * 512 + wave * 64;            // wave-uniform base granule
    const int p = g0 + lane;
    const int row = p >> 3, c = p & 7;
    load_lds16(Qb + (size_t)(qt + row) * H + ((c ^ (row & 7)) * 8),
               &smem[2048 + (g0 >> 8) * 4096 + (g0 & 255) * 8]);
  }
  // per-thread staging source pointers (advance by constants per tile)
  const int htid = tid & 255;
  const unsigned short* pK; const unsigned short* pV;
  {
    int row = htid >> 3, c = htid & 7;
    pK = Kb + (size_t)(kvoff + row) * H + ((c ^ (row & 7)) * 8);
    int d = htid >> 2, kvc = htid & 3;
    int sg = kvc ^ ((d >> 1) & 3);
    pV = Vb + (size_t)d * 2048 + kvoff + sg * 8;
  }
  load_lds16(pK, &sK0[(w4 * 64) * 8]);
  load_lds16(pV, &sV0[(w4 * 64) * 8]);
  pK += 32 * H; pV += 32;

  asm volatile("s_waitcnt vmcnt(2)" ::: "memory");  // Q landed; K0/V0 still in flight
  __builtin_amdgcn_sched_barrier(0);
  __builtin_amdgcn_s_barrier();                     // all waves' Q visible

  bf16x8 qf[2][2];
  {
    const unsigned short* qreg = smem + 2048 + w4 * 4096;
#pragma unroll
    for (int m = 0; m < 2; m++) {
      const int row = w4 * 32 + m * 16 + l16;
      const int qm = mask[(size_t)b * S + qt + row];   // query-axis mask (matches ref)
#pragma unroll
      for (int ks = 0; ks < 2; ks++) {
        bf16x8 v = *(const bf16x8*)&qreg[(m * 16 + l16) * 64 + (((ks * 4 + hi) ^ swz) * 8)];
        u32x4 u = __builtin_bit_cast(u32x4, v);
#pragma unroll
        for (int c = 0; c < 4; c++) u[c] = qm ? u[c] : 0u;
        qf[m][ks] = __builtin_bit_cast(bf16x8, u);
      }
    }
  }
  // Q-frag LDS reads must complete before any wave stages t=1 into the buf-1 regions;
  // each wave drains its own reads here, the t=0 loop barrier globalizes it.
  asm volatile("s_waitcnt lgkmcnt(0)" ::: "memory");
  __builtin_amdgcn_sched_barrier(0);

  const f32x4 c16 = {-16.0f, -16.0f, -16.0f, -16.0f};   // hoisted softmax shift
  float lsum[2] = {0.f, 0.f};
  f32x4 oacc[2][4] = {};

  for (int t = 0; t < 32; t++) {
    const int cur = t & 1;
    // single-barrier pipeline point: stage(t) landed everywhere + compute(t-1)
    // finished everywhere (and at t=0: Q-frag reads done everywhere).
    asm volatile("s_waitcnt vmcnt(0)" ::: "memory");
    __builtin_amdgcn_sched_barrier(0);
    __builtin_amdgcn_s_barrier();

    // issue next-tile staging immediately; it lands during compute(t)
    if (t < 31) {
      unsigned short* nK = cur ? sK0 : sK1;
      unsigned short* nV = cur ? sV0 : sV1;
      load_lds16(pK, &nK[(w4 * 64) * 8]);
      load_lds16(pV, &nV[(w4 * 64) * 8]);
      pK += 32 * H; pV += 32;
    }

    const unsigned short* kb = cur ? sK1 : sK0;
    const unsigned short* vb = cur ? sV1 : sV0;

    // ---- QK^T swapped (32 kv): sf[m][j] = S - 16 (C-operand bake, no per-tile movs)
    f32x4 sf[2][2];
    __builtin_amdgcn_s_setprio(1);
#pragma unroll
    for (int j = 0; j < 2; j++) {
      const int ro = j * 1024;
      bf16x8 kf0 = *(const bf16x8*)&kb[ro + kinv0];
      bf16x8 kf1 = *(const bf16x8*)&kb[ro + kinv1];
#pragma unroll
      for (int m = 0; m < 2; m++) {
        f32x4 a = __builtin_amdgcn_mfma_f32_16x16x32_bf16(kf0, qf[m][0], c16, 0, 0, 0);
        sf[m][j] = __builtin_amdgcn_mfma_f32_16x16x32_bf16(kf1, qf[m][1], a, 0, 0, 0);
      }
    }
    __builtin_amdgcn_s_setprio(0);

    // ---- constant-max softmax: P = exp2(s')
#pragma unroll
    for (int m = 0; m < 2; m++) {
#pragma unroll
      for (int j = 0; j < 2; j++)
#pragma unroll
        for (int r = 0; r < 4; r++)
          sf[m][j][r] = fexp2(sf[m][j][r]);
      f32x4 c4 = sf[m][0] + sf[m][1];
      lsum[m] += (c4[0] + c4[1]) + (c4[2] + c4[3]);
    }

    // ---- P repack (permlane) + PV (one 32-kv window); V-frag shared across m
    {
      bf16x8 af0 = repack_af(sf[0][0], sf[0][1]);
      bf16x8 af1 = repack_af(sf[1][0], sf[1][1]);
      __builtin_amdgcn_s_setprio(1);
#pragma unroll
      for (int n = 0; n < 4; n++) {
        bf16x8 vf = *(const bf16x8*)&vb[n * 512 + vinv];
        oacc[0][n] = __builtin_amdgcn_mfma_f32_16x16x32_bf16(af0, vf, oacc[0][n], 0, 0, 0);
        oacc[1][n] = __builtin_amdgcn_mfma_f32_16x16x32_bf16(af1, vf, oacc[1][n], 0, 0, 0);
      }
      __builtin_amdgcn_s_setprio(0);
    }
  }

  // ---- epilogue: reduce lsum across hi groups; combine halves via 2-pass LDS
#pragma unroll
  for (int m = 0; m < 2; m++) {
    lsum[m] += __shfl_xor(lsum[m], 16);
    lsum[m] += __shfl_xor(lsum[m], 32);
  }

  __syncthreads();   // all waves done reading K/V LDS before sO overwrite

  float* sO = (float*)smem;            // [64][66] f32 = 16896B
  float* sL = (float*)smem + 64 * 66;  // 64 f32

#pragma unroll
  for (int pass = 0; pass < 2; pass++) {
    if (half == 1 && (w4 >> 1) == pass) {
      const int lrow = (w4 & 1) * 32;
#pragma unroll
      for (int m = 0; m < 2; m++) {
        if (hi == 0) sL[lrow + m * 16 + l16] = lsum[m];
#pragma unroll
        for (int n = 0; n < 4; n++)
#pragma unroll
          for (int r = 0; r < 4; r++)
            sO[(lrow + m * 16 + hi * 4 + r) * 66 + n * 16 + l16] = oacc[m][n][r];
      }
    }
    __syncthreads();
    if (half == 0 && (w4 >> 1) == pass) {
      const int lrow = (w4 & 1) * 32;
#pragma unroll
      for (int m = 0; m < 2; m++) {
        float lt = lsum[m] + sL[lrow + m * 16 + l16];
        float lr[4];
#pragma unroll
        for (int r = 0; r < 4; r++) lr[r] = 1.0f / __shfl(lt, hi * 4 + r);
#pragma unroll
        for (int n = 0; n < 4; n++)
#pragma unroll
          for (int r = 0; r < 4; r++) {
            int lq = lrow + m * 16 + hi * 4 + r;
            int col = n * 16 + l16;
            float val = (oacc[m][n][r] + sO[lq * 66 + col]) * lr[r];
            Yb[((size_t)b * S + qt + pass * 64 + lq) * H + h * 64 + col] = f2bf(val);
          }
      }
    }
    __syncthreads();
  }
}

// ---------------------------------------------------------------- launch
extern "C" void kernel_launch(void* const* d_in, const int* in_sizes, int n_in,
                              void* d_out, int out_size, void* d_ws, size_t ws_size,
                              hipStream_t stream)
{
  const float* q  = (const float*)d_in[0];
  const float* k  = (const float*)d_in[1];
  const float* v  = (const float*)d_in[2];
  const int*  mask = (const int*)d_in[3];
  const float* Wq = (const float*)d_in[4];
  const float* bq = (const float*)d_in[5];
  const float* Wk = (const float*)d_in[6];
  const float* bk = (const float*)d_in[7];
  const float* Wv = (const float*)d_in[8];
  const float* bv = (const float*)d_in[9];
  const float* Wo = (const float*)d_in[10];
  const float* bo = (const float*)d_in[11];

  unsigned short* ws  = (unsigned short*)d_ws;
  unsigned short* qb  = ws;                 //  0..4  EL
  unsigned short* kb  = ws + 4 * EL;        //  4..8
  unsigned short* vb  = ws + 8 * EL;        //  8..12
  unsigned short* wqb = ws + 12 * EL;       // 12..13
  unsigned short* wkb = ws + 13 * EL;       // 13..14
  unsigned short* wvb = ws + 14 * EL;       // 14..15
  unsigned short* wob = ws + 15 * EL;       // 15..16
  unsigned short* Qp  = ws + 16 * EL;       // 16..20
  unsigned short* Kp  = ws + 20 * EL;       // 20..24
  unsigned short* Vt  = ws + 24 * EL;       // 24..28  [32][64][2048] bf16
  unsigned short* Yb  = ws + 28 * EL;       // 28..32

  convert_all<<<2048, 256, 0, stream>>>(q, k, v, Wq, Wk, Wv, Wo, ws);
  qkv_gemm<<<dim3(8, 32, 3), 256, 0, stream>>>(qb, kb, vb, wqb, wkb, wvb,
                                               bq, bk, bv, Qp, Kp, Vt);
  attn_kernel<<<dim3(16, 16, 2), 512, 0, stream>>>(Qp, Kp, Vt, mask, Yb);
  out_gemm<<<dim3(16, 32), 256, 0, stream>>>(Yb, wob, bo, (float*)d_out);
}

// Round 18
// 106.436 us; speedup vs baseline: 1.3692x; 1.3692x over previous
//
#include <hip/hip_runtime.h>
#include <hip/hip_bf16.h>
#include <cstdint>

#define EL 1048576ull   // 1Mi elements

typedef __bf16 bf16_t;
typedef bf16_t bf16x8 __attribute__((ext_vector_type(8)));
typedef float  f32x4  __attribute__((ext_vector_type(4)));
typedef unsigned int u32x2 __attribute__((ext_vector_type(2)));
typedef unsigned int u32x4 __attribute__((ext_vector_type(4)));

__device__ __forceinline__ unsigned short f2bf(float f) {
  unsigned int u = __builtin_bit_cast(unsigned int, f);
  u += 0x7FFFu + ((u >> 16) & 1u);   // RNE
  return (unsigned short)(u >> 16);
}

// pack 2 f32 -> 2 bf16 in one u32 (lo -> low half), RNE; proven round 5
__device__ __forceinline__ unsigned int cvtpk(float lo, float hi2) {
  unsigned int r;
  asm("v_cvt_pk_bf16_f32 %0, %1, %2" : "=v"(r) : "v"(lo), "v"(hi2));
  return r;
}

__device__ __forceinline__ float fexp2(float x) {
#if __has_builtin(__builtin_amdgcn_exp2f)
  return __builtin_amdgcn_exp2f(x);
#else
  return exp2f(x);
#endif
}

typedef __attribute__((address_space(1))) void as1_void;
typedef __attribute__((address_space(3))) void as3_void;
__device__ __forceinline__ void load_lds16(const void* g, void* l) {
  __builtin_amdgcn_global_load_lds((as1_void*)g, (as3_void*)l, 16, 0, 0);
}

// P repack via permlane swaps (VALU, no LDS pipe); proven round 6
__device__ __forceinline__ bf16x8 repack_af(const f32x4 s0v, const f32x4 s1v) {
  unsigned int c00 = cvtpk(s0v[0], s0v[1]);
  unsigned int c01 = cvtpk(s0v[2], s0v[3]);
  unsigned int c10 = cvtpk(s1v[0], s1v[1]);
  unsigned int c11 = cvtpk(s1v[2], s1v[3]);
  asm("v_permlane32_swap_b32 %0, %1" : "+v"(c00), "+v"(c10));
  asm("v_permlane16_swap_b32 %0, %1" : "+v"(c00), "+v"(c10));
  asm("v_permlane32_swap_b32 %0, %1" : "+v"(c01), "+v"(c11));
  asm("v_permlane16_swap_b32 %0, %1" : "+v"(c01), "+v"(c11));
  u32x4 wd; wd[0] = c00; wd[1] = c01; wd[2] = c10; wd[3] = c11;
  return __builtin_bit_cast(bf16x8, wd);
}

// ---------------------------------------------------------------- convert
__global__ __launch_bounds__(256) void convert_all(
    const float* __restrict__ q, const float* __restrict__ k, const float* __restrict__ v,
    const float* __restrict__ wq, const float* __restrict__ wk,
    const float* __restrict__ wv, const float* __restrict__ wo,
    unsigned short* __restrict__ ws)
{
  const size_t total_v4 = 4 * EL; // 16M elems / 4
  for (size_t v4 = (size_t)blockIdx.x * blockDim.x + threadIdx.x; v4 < total_v4;
       v4 += (size_t)gridDim.x * blockDim.x) {
    size_t e = v4 * 4;
    unsigned seg = (unsigned)(e >> 20);
    const float* s; size_t base;
    if      (seg < 4)   { s = q;  base = 0; }
    else if (seg < 8)   { s = k;  base = 4*EL; }
    else if (seg < 12)  { s = v;  base = 8*EL; }
    else if (seg == 12) { s = wq; base = 12*EL; }
    else if (seg == 13) { s = wk; base = 13*EL; }
    else if (seg == 14) { s = wv; base = 14*EL; }
    else                { s = wo; base = 15*EL; }
    const float4 f = *(const float4*)(s + (e - base));
    ushort4 o;
    o.x = f2bf(f.x); o.y = f2bf(f.y); o.z = f2bf(f.z); o.w = f2bf(f.w);
    *(ushort4*)(ws + e) = o;
  }
}

// ---------------------------------------------------------------- GEMM main loop (acc += A * B^T)
template <int BM, int BN, int WM, int WN>
__device__ __forceinline__ void gemm_bt_main(
    const unsigned short* __restrict__ A,
    const unsigned short* __restrict__ B,
    f32x4 (&acc)[BM / WM / 16][BN / WN / 16],
    const int tm, const int tn)
{
  constexpr int K = 1024, BK = 64;
  constexpr int AM = BM / WM / 16, AN = BN / WN / 16;
  __shared__ __align__(16) unsigned short sA[BM * BK];
  __shared__ __align__(16) unsigned short sB[BN * BK];
  const int tid  = threadIdx.x;
  const int wave = tid >> 6, lane = tid & 63;
  const int wm = wave / WN, wn = wave % WN;
  const int l16 = lane & 15, hi = lane >> 4, swz = l16 & 7;

  for (int k0 = 0; k0 < K; k0 += BK) {
    __syncthreads();
#pragma unroll
    for (int i = 0; i < BM * 8 / 256; i++) {
      int p = i * 256 + tid;
      int row = p >> 3, c = p & 7;
      load_lds16(A + (size_t)(tm + row) * K + k0 + ((c ^ (row & 7)) * 8),
                 &sA[(i * 256 + wave * 64) * 8]);
    }
#pragma unroll
    for (int i = 0; i < BN * 8 / 256; i++) {
      int p = i * 256 + tid;
      int row = p >> 3, c = p & 7;
      load_lds16(B + (size_t)(tn + row) * K + k0 + ((c ^ (row & 7)) * 8),
                 &sB[(i * 256 + wave * 64) * 8]);
    }
    __syncthreads();

#pragma unroll
    for (int kk = 0; kk < 2; kk++) {
      bf16x8 af[AM], bfr[AN];
#pragma unroll
      for (int i = 0; i < AM; i++) {
        int row = wm * (BM / WM) + i * 16 + l16;
        af[i] = *(const bf16x8*)&sA[row * BK + (((kk * 4 + hi) ^ swz) * 8)];
      }
#pragma unroll
      for (int j = 0; j < AN; j++) {
        int row = wn * (BN / WN) + j * 16 + l16;
        bfr[j] = *(const bf16x8*)&sB[row * BK + (((kk * 4 + hi) ^ swz) * 8)];
      }
#pragma unroll
      for (int i = 0; i < AM; i++)
#pragma unroll
        for (int j = 0; j < AN; j++)
          acc[i][j] = __builtin_amdgcn_mfma_f32_16x16x32_bf16(af[i], bfr[j], acc[i][j], 0, 0, 0);
    }
  }
}

// ---------------------------------------------------------------- QKV projections
// Grid (8, 32, 3). XCD = blockIdx.x. A-panel's 8 sharers pinned to one XCD.
__global__ __launch_bounds__(256, 3) void qkv_gemm(
    const unsigned short* qb, const unsigned short* kb, const unsigned short* vb,
    const unsigned short* wqb, const unsigned short* wkb, const unsigned short* wvb,
    const float* bq, const float* bk, const float* bv,
    unsigned short* Qp, unsigned short* Kp, unsigned short* Vt)
{
  const unsigned short* A; const unsigned short* B; const float* bias;
  if (blockIdx.z == 0)      { A = qb; B = wqb; bias = bq; }
  else if (blockIdx.z == 1) { A = kb; B = wkb; bias = bk; }
  else                      { A = vb; B = wvb; bias = bv; }

  const int xd = blockIdx.x, yd = blockIdx.y;
  const int mt = xd + 8 * (yd & 3);    // A-panel id 0..31, pinned to XCD xd
  const int nt = yd >> 2;              // 0..7
  const int tm = mt * 128, tn = nt * 128;

  f32x4 acc[4][4] = {};
  gemm_bt_main<128, 128, 2, 2>(A, B, acc, tm, tn);

  const int tid = threadIdx.x, wave = tid >> 6, lane = tid & 63;
  const int wm = wave >> 1, wn = wave & 1;
  const int l16 = lane & 15, hi = lane >> 4;

  if (blockIdx.z < 2) {
    unsigned short* C = (blockIdx.z == 0) ? Qp : Kp;
    const float scale = (blockIdx.z == 0) ? 0.18033688011112042f : 1.0f; // 0.125*log2(e)
#pragma unroll
    for (int i = 0; i < 4; i++) {
      int row0 = tm + wm * 64 + i * 16 + hi * 4;
#pragma unroll
      for (int j = 0; j < 4; j++) {
        int col = tn + wn * 64 + j * 16 + l16;
        float bv2 = bias[col];
#pragma unroll
        for (int r = 0; r < 4; r++)
          C[(size_t)(row0 + r) * 1024 + col] = f2bf((acc[i][j][r] + bv2) * scale);
      }
    }
  } else {
    // transposed V write: lane's 4 rows are 4 consecutive s -> one 8B store
#pragma unroll
    for (int i = 0; i < 4; i++) {
      int row0 = tm + wm * 64 + i * 16 + hi * 4;
      int bb = row0 >> 11, s = row0 & 2047;
#pragma unroll
      for (int j = 0; j < 4; j++) {
        int col = tn + wn * 64 + j * 16 + l16;
        int hh = col >> 6, d = col & 63;
        float bv2 = bias[col];
        u32x2 w;
        w[0] = cvtpk(acc[i][j][0] + bv2, acc[i][j][1] + bv2);
        w[1] = cvtpk(acc[i][j][2] + bv2, acc[i][j][3] + bv2);
        *(u32x2*)&Vt[((size_t)(bb * 16 + hh) * 64 + d) * 2048 + s] = w;
      }
    }
  }
}

// Grid (16, 32). XCD = x%8. Pin each Yb A-panel's 16 sharers to one XCD.
__global__ __launch_bounds__(256, 2) void out_gemm(
    const unsigned short* Yb, const unsigned short* wob, const float* bo, float* out)
{
  const int xd = blockIdx.x, yd = blockIdx.y;
  const int mt = (xd & 7) + 8 * (yd & 3);   // 0..31, pinned to XCD xd&7
  const int nt = (xd >> 3) + 2 * (yd >> 2); // 0..15
  const int tm = mt * 128, tn = nt * 64;

  f32x4 acc[2][4] = {};
  gemm_bt_main<128, 64, 4, 1>(Yb, wob, acc, tm, tn);

  const int tid = threadIdx.x, wave = tid >> 6, lane = tid & 63;
  const int l16 = lane & 15, hi = lane >> 4;
#pragma unroll
  for (int i = 0; i < 2; i++) {
    int row0 = tm + wave * 32 + i * 16 + hi * 4;
#pragma unroll
    for (int j = 0; j < 4; j++) {
      int col = tn + j * 16 + l16;
      float bv2 = bo[col];
#pragma unroll
      for (int r = 0; r < 4; r++)
        out[(size_t)(row0 + r) * 1024 + col] = acc[i][j][r] + bv2;
    }
  }
}

// ---------------------------------------------------------------- flash attention
// IN-BLOCK KV-SPLIT, KVBLK=32, 32KB LDS. launch_bounds(512,4): 128-VGPR cap ->
// no spills (r17's (512,6) cap=85 forced ~72MB of scratch traffic); natural
// allocation ~50-60 VGPR -> 4 blocks/CU possible (32 waves/CU = 8/SIMD).
// 8 waves x 32 q-rows; waves 0-3 kv[0,1024), waves 4-7 kv[1024,2048), same 128 q.
// Single-barrier pipeline per tile. Constant-max softmax (exp2(s-16), shift baked
// into hoisted MFMA C-operand). Q prologue staged across the four idle buf-1
// regions. Halves combine via 2-pass LDS epilogue (sO[64][66] fits 32KB).
__global__ __launch_bounds__(512, 4) void attn_kernel(
    const unsigned short* __restrict__ Qp, const unsigned short* __restrict__ Kp,
    const unsigned short* __restrict__ Vt, const int* __restrict__ mask,
    unsigned short* __restrict__ Yb)
{
  constexpr int S = 2048, H = 1024;
  __shared__ __align__(16) unsigned short smem[16384];   // 32KB
  // shorts layout: K: h0b0[0,2048) h0b1[2048,4096) h1b0[4096,6144) h1b1[6144,8192)
  //                V: 8192 + same. Q prologue -> the four buf-1 regions.

  const int tid = threadIdx.x, wave = tid >> 6, lane = tid & 63;
  const int l16 = lane & 15, hi = lane >> 4, swz = l16 & 7;
  const int half = wave >> 2, w4 = wave & 3;
  const int kvoff = half * 1024;
  const int xd = blockIdx.x, hd = blockIdx.y;
  const int h  = (xd & 7) + 8 * (hd & 1);            // pinned to XCD xd&7
  const int qt = ((xd >> 3) + 2 * (hd >> 1)) * 128;  // 0..15 q-tile
  const int b = blockIdx.z, bh = b * 16 + h;
  const unsigned short* Qb = Qp + (size_t)b * S * H + (size_t)h * 64;
  const unsigned short* Kb = Kp + (size_t)b * S * H + (size_t)h * 64;
  const unsigned short* Vb = Vt + (size_t)bh * 64 * 2048;

  unsigned short* sK0 = smem + half * 4096;
  unsigned short* sK1 = sK0 + 2048;
  unsigned short* sV0 = smem + 8192 + half * 4096;
  unsigned short* sV1 = sV0 + 2048;

  // loop-invariant LDS read offsets (shorts)
  const int kinv0 = l16 * 64 + ((hi ^ swz) * 8);               // K row stride 64
  const int kinv1 = l16 * 64 + (((4 + hi) ^ swz) * 8);
  const int vinv  = l16 * 32 + ((hi ^ ((l16 >> 1) & 3)) * 8);  // V row stride 32

  // ---- stage Q (128x64 = 16KB) into the four idle buf-1 regions
#pragma unroll
  for (int i = 0; i < 2; i++) {
    const int g0 = i * 512 + wave * 64;            // wave-uniform base granule
    const int p = g0 + lane;
    const int row = p >> 3, c = p & 7;
    load_lds16(Qb + (size_t)(qt + row) * H + ((c ^ (row & 7)) * 8),
               &smem[2048 + (g0 >> 8) * 4096 + (g0 & 255) * 8]);
  }
  // per-thread staging source pointers (advance by constants per tile)
  const int htid = tid & 255;
  const unsigned short* pK; const unsigned short* pV;
  {
    int row = htid >> 3, c = htid & 7;
    pK = Kb + (size_t)(kvoff + row) * H + ((c ^ (row & 7)) * 8);
    int d = htid >> 2, kvc = htid & 3;
    int sg = kvc ^ ((d >> 1) & 3);
    pV = Vb + (size_t)d * 2048 + kvoff + sg * 8;
  }
  load_lds16(pK, &sK0[(w4 * 64) * 8]);
  load_lds16(pV, &sV0[(w4 * 64) * 8]);
  pK += 32 * H; pV += 32;

  asm volatile("s_waitcnt vmcnt(2)" ::: "memory");  // Q landed; K0/V0 still in flight
  __builtin_amdgcn_sched_barrier(0);
  __builtin_amdgcn_s_barrier();                     // all waves' Q visible

  bf16x8 qf[2][2];
  {
    const unsigned short* qreg = smem + 2048 + w4 * 4096;
#pragma unroll
    for (int m = 0; m < 2; m++) {
      const int row = w4 * 32 + m * 16 + l16;
      const int qm = mask[(size_t)b * S + qt + row];   // query-axis mask (matches ref)
#pragma unroll
      for (int ks = 0; ks < 2; ks++) {
        bf16x8 v = *(const bf16x8*)&qreg[(m * 16 + l16) * 64 + (((ks * 4 + hi) ^ swz) * 8)];
        u32x4 u = __builtin_bit_cast(u32x4, v);
#pragma unroll
        for (int c = 0; c < 4; c++) u[c] = qm ? u[c] : 0u;
        qf[m][ks] = __builtin_bit_cast(bf16x8, u);
      }
    }
  }
  // Q-frag LDS reads must complete before any wave stages t=1 into the buf-1 regions;
  // each wave drains its own reads here, the t=0 loop barrier globalizes it.
  asm volatile("s_waitcnt lgkmcnt(0)" ::: "memory");
  __builtin_amdgcn_sched_barrier(0);

  const f32x4 c16 = {-16.0f, -16.0f, -16.0f, -16.0f};   // hoisted softmax shift
  float lsum[2] = {0.f, 0.f};
  f32x4 oacc[2][4] = {};

  for (int t = 0; t < 32; t++) {
    const int cur = t & 1;
    // single-barrier pipeline point: stage(t) landed everywhere + compute(t-1)
    // finished everywhere (and at t=0: Q-frag reads done everywhere).
    asm volatile("s_waitcnt vmcnt(0)" ::: "memory");
    __builtin_amdgcn_sched_barrier(0);
    __builtin_amdgcn_s_barrier();

    // issue next-tile staging immediately; it lands during compute(t)
    if (t < 31) {
      unsigned short* nK = cur ? sK0 : sK1;
      unsigned short* nV = cur ? sV0 : sV1;
      load_lds16(pK, &nK[(w4 * 64) * 8]);
      load_lds16(pV, &nV[(w4 * 64) * 8]);
      pK += 32 * H; pV += 32;
    }

    const unsigned short* kb = cur ? sK1 : sK0;
    const unsigned short* vb = cur ? sV1 : sV0;

    // ---- QK^T swapped (32 kv): sf[m][j] = S - 16 (C-operand bake, no per-tile movs)
    f32x4 sf[2][2];
    __builtin_amdgcn_s_setprio(1);
#pragma unroll
    for (int j = 0; j < 2; j++) {
      const int ro = j * 1024;
      bf16x8 kf0 = *(const bf16x8*)&kb[ro + kinv0];
      bf16x8 kf1 = *(const bf16x8*)&kb[ro + kinv1];
#pragma unroll
      for (int m = 0; m < 2; m++) {
        f32x4 a = __builtin_amdgcn_mfma_f32_16x16x32_bf16(kf0, qf[m][0], c16, 0, 0, 0);
        sf[m][j] = __builtin_amdgcn_mfma_f32_16x16x32_bf16(kf1, qf[m][1], a, 0, 0, 0);
      }
    }
    __builtin_amdgcn_s_setprio(0);

    // ---- constant-max softmax: P = exp2(s')
#pragma unroll
    for (int m = 0; m < 2; m++) {
#pragma unroll
      for (int j = 0; j < 2; j++)
#pragma unroll
        for (int r = 0; r < 4; r++)
          sf[m][j][r] = fexp2(sf[m][j][r]);
      f32x4 c4 = sf[m][0] + sf[m][1];
      lsum[m] += (c4[0] + c4[1]) + (c4[2] + c4[3]);
    }

    // ---- P repack (permlane) + PV (one 32-kv window); V-frag shared across m
    {
      bf16x8 af0 = repack_af(sf[0][0], sf[0][1]);
      bf16x8 af1 = repack_af(sf[1][0], sf[1][1]);
      __builtin_amdgcn_s_setprio(1);
#pragma unroll
      for (int n = 0; n < 4; n++) {
        bf16x8 vf = *(const bf16x8*)&vb[n * 512 + vinv];
        oacc[0][n] = __builtin_amdgcn_mfma_f32_16x16x32_bf16(af0, vf, oacc[0][n], 0, 0, 0);
        oacc[1][n] = __builtin_amdgcn_mfma_f32_16x16x32_bf16(af1, vf, oacc[1][n], 0, 0, 0);
      }
      __builtin_amdgcn_s_setprio(0);
    }
  }

  // ---- epilogue: reduce lsum across hi groups; combine halves via 2-pass LDS
#pragma unroll
  for (int m = 0; m < 2; m++) {
    lsum[m] += __shfl_xor(lsum[m], 16);
    lsum[m] += __shfl_xor(lsum[m], 32);
  }

  __syncthreads();   // all waves done reading K/V LDS before sO overwrite

  float* sO = (float*)smem;            // [64][66] f32 = 16896B
  float* sL = (float*)smem + 64 * 66;  // 64 f32

#pragma unroll
  for (int pass = 0; pass < 2; pass++) {
    if (half == 1 && (w4 >> 1) == pass) {
      const int lrow = (w4 & 1) * 32;
#pragma unroll
      for (int m = 0; m < 2; m++) {
        if (hi == 0) sL[lrow + m * 16 + l16] = lsum[m];
#pragma unroll
        for (int n = 0; n < 4; n++)
#pragma unroll
          for (int r = 0; r < 4; r++)
            sO[(lrow + m * 16 + hi * 4 + r) * 66 + n * 16 + l16] = oacc[m][n][r];
      }
    }
    __syncthreads();
    if (half == 0 && (w4 >> 1) == pass) {
      const int lrow = (w4 & 1) * 32;
#pragma unroll
      for (int m = 0; m < 2; m++) {
        float lt = lsum[m] + sL[lrow + m * 16 + l16];
        float lr[4];
#pragma unroll
        for (int r = 0; r < 4; r++) lr[r] = 1.0f / __shfl(lt, hi * 4 + r);
#pragma unroll
        for (int n = 0; n < 4; n++)
#pragma unroll
          for (int r = 0; r < 4; r++) {
            int lq = lrow + m * 16 + hi * 4 + r;
            int col = n * 16 + l16;
            float val = (oacc[m][n][r] + sO[lq * 66 + col]) * lr[r];
            Yb[((size_t)b * S + qt + pass * 64 + lq) * H + h * 64 + col] = f2bf(val);
          }
      }
    }
    __syncthreads();
  }
}

// ---------------------------------------------------------------- launch
extern "C" void kernel_launch(void* const* d_in, const int* in_sizes, int n_in,
                              void* d_out, int out_size, void* d_ws, size_t ws_size,
                              hipStream_t stream)
{
  const float* q  = (const float*)d_in[0];
  const float* k  = (const float*)d_in[1];
  const float* v  = (const float*)d_in[2];
  const int*  mask = (const int*)d_in[3];
  const float* Wq = (const float*)d_in[4];
  const float* bq = (const float*)d_in[5];
  const float* Wk = (const float*)d_in[6];
  const float* bk = (const float*)d_in[7];
  const float* Wv = (const float*)d_in[8];
  const float* bv = (const float*)d_in[9];
  const float* Wo = (const float*)d_in[10];
  const float* bo = (const float*)d_in[11];

  unsigned short* ws  = (unsigned short*)d_ws;
  unsigned short* qb  = ws;                 //  0..4  EL
  unsigned short* kb  = ws + 4 * EL;        //  4..8
  unsigned short* vb  = ws + 8 * EL;        //  8..12
  unsigned short* wqb = ws + 12 * EL;       // 12..13
  unsigned short* wkb = ws + 13 * EL;       // 13..14
  unsigned short* wvb = ws + 14 * EL;       // 14..15
  unsigned short* wob = ws + 15 * EL;       // 15..16
  unsigned short* Qp  = ws + 16 * EL;       // 16..20
  unsigned short* Kp  = ws + 20 * EL;       // 20..24
  unsigned short* Vt  = ws + 24 * EL;       // 24..28  [32][64][2048] bf16
  unsigned short* Yb  = ws + 28 * EL;       // 28..32

  convert_all<<<2048, 256, 0, stream>>>(q, k, v, Wq, Wk, Wv, Wo, ws);
  qkv_gemm<<<dim3(8, 32, 3), 256, 0, stream>>>(qb, kb, vb, wqb, wkb, wvb,
                                               bq, bk, bv, Qp, Kp, Vt);
  attn_kernel<<<dim3(16, 16, 2), 512, 0, stream>>>(Qp, Kp, Vt, mask, Yb);
  out_gemm<<<dim3(16, 32), 256, 0, stream>>>(Yb, wob, bo, (float*)d_out);
}

// Round 19
// 103.992 us; speedup vs baseline: 1.4013x; 1.0235x over previous
//
#include <hip/hip_runtime.h>
#include <hip/hip_bf16.h>
#include <cstdint>

#define EL 1048576ull   // 1Mi elements

typedef __bf16 bf16_t;
typedef bf16_t bf16x8 __attribute__((ext_vector_type(8)));
typedef float  f32x4  __attribute__((ext_vector_type(4)));
typedef unsigned int u32x2 __attribute__((ext_vector_type(2)));
typedef unsigned int u32x4 __attribute__((ext_vector_type(4)));

__device__ __forceinline__ unsigned short f2bf(float f) {
  unsigned int u = __builtin_bit_cast(unsigned int, f);
  u += 0x7FFFu + ((u >> 16) & 1u);   // RNE
  return (unsigned short)(u >> 16);
}

// pack 2 f32 -> 2 bf16 in one u32 (lo -> low half), RNE; proven round 5
__device__ __forceinline__ unsigned int cvtpk(float lo, float hi2) {
  unsigned int r;
  asm("v_cvt_pk_bf16_f32 %0, %1, %2" : "=v"(r) : "v"(lo), "v"(hi2));
  return r;
}

__device__ __forceinline__ float fexp2(float x) {
#if __has_builtin(__builtin_amdgcn_exp2f)
  return __builtin_amdgcn_exp2f(x);
#else
  return exp2f(x);
#endif
}

typedef __attribute__((address_space(1))) void as1_void;
typedef __attribute__((address_space(3))) void as3_void;
__device__ __forceinline__ void load_lds16(const void* g, void* l) {
  __builtin_amdgcn_global_load_lds((as1_void*)g, (as3_void*)l, 16, 0, 0);
}

// P repack via permlane swaps (VALU, no LDS pipe); proven round 6
__device__ __forceinline__ bf16x8 repack_af(const f32x4 s0v, const f32x4 s1v) {
  unsigned int c00 = cvtpk(s0v[0], s0v[1]);
  unsigned int c01 = cvtpk(s0v[2], s0v[3]);
  unsigned int c10 = cvtpk(s1v[0], s1v[1]);
  unsigned int c11 = cvtpk(s1v[2], s1v[3]);
  asm("v_permlane32_swap_b32 %0, %1" : "+v"(c00), "+v"(c10));
  asm("v_permlane16_swap_b32 %0, %1" : "+v"(c00), "+v"(c10));
  asm("v_permlane32_swap_b32 %0, %1" : "+v"(c01), "+v"(c11));
  asm("v_permlane16_swap_b32 %0, %1" : "+v"(c01), "+v"(c11));
  u32x4 wd; wd[0] = c00; wd[1] = c01; wd[2] = c10; wd[3] = c11;
  return __builtin_bit_cast(bf16x8, wd);
}

// ---------------------------------------------------------------- convert
__global__ __launch_bounds__(256) void convert_all(
    const float* __restrict__ q, const float* __restrict__ k, const float* __restrict__ v,
    const float* __restrict__ wq, const float* __restrict__ wk,
    const float* __restrict__ wv, const float* __restrict__ wo,
    unsigned short* __restrict__ ws)
{
  const size_t total_v4 = 4 * EL; // 16M elems / 4
  for (size_t v4 = (size_t)blockIdx.x * blockDim.x + threadIdx.x; v4 < total_v4;
       v4 += (size_t)gridDim.x * blockDim.x) {
    size_t e = v4 * 4;
    unsigned seg = (unsigned)(e >> 20);
    const float* s; size_t base;
    if      (seg < 4)   { s = q;  base = 0; }
    else if (seg < 8)   { s = k;  base = 4*EL; }
    else if (seg < 12)  { s = v;  base = 8*EL; }
    else if (seg == 12) { s = wq; base = 12*EL; }
    else if (seg == 13) { s = wk; base = 13*EL; }
    else if (seg == 14) { s = wv; base = 14*EL; }
    else                { s = wo; base = 15*EL; }
    const float4 f = *(const float4*)(s + (e - base));
    ushort4 o;
    o.x = f2bf(f.x); o.y = f2bf(f.y); o.z = f2bf(f.z); o.w = f2bf(f.w);
    *(ushort4*)(ws + e) = o;
  }
}

// ---------------------------------------------------------------- GEMM main loop (acc += A * B^T)
template <int BM, int BN, int WM, int WN>
__device__ __forceinline__ void gemm_bt_main(
    const unsigned short* __restrict__ A,
    const unsigned short* __restrict__ B,
    f32x4 (&acc)[BM / WM / 16][BN / WN / 16],
    const int tm, const int tn)
{
  constexpr int K = 1024, BK = 64;
  constexpr int AM = BM / WM / 16, AN = BN / WN / 16;
  __shared__ __align__(16) unsigned short sA[BM * BK];
  __shared__ __align__(16) unsigned short sB[BN * BK];
  const int tid  = threadIdx.x;
  const int wave = tid >> 6, lane = tid & 63;
  const int wm = wave / WN, wn = wave % WN;
  const int l16 = lane & 15, hi = lane >> 4, swz = l16 & 7;

  for (int k0 = 0; k0 < K; k0 += BK) {
    __syncthreads();
#pragma unroll
    for (int i = 0; i < BM * 8 / 256; i++) {
      int p = i * 256 + tid;
      int row = p >> 3, c = p & 7;
      load_lds16(A + (size_t)(tm + row) * K + k0 + ((c ^ (row & 7)) * 8),
                 &sA[(i * 256 + wave * 64) * 8]);
    }
#pragma unroll
    for (int i = 0; i < BN * 8 / 256; i++) {
      int p = i * 256 + tid;
      int row = p >> 3, c = p & 7;
      load_lds16(B + (size_t)(tn + row) * K + k0 + ((c ^ (row & 7)) * 8),
                 &sB[(i * 256 + wave * 64) * 8]);
    }
    __syncthreads();

#pragma unroll
    for (int kk = 0; kk < 2; kk++) {
      bf16x8 af[AM], bfr[AN];
#pragma unroll
      for (int i = 0; i < AM; i++) {
        int row = wm * (BM / WM) + i * 16 + l16;
        af[i] = *(const bf16x8*)&sA[row * BK + (((kk * 4 + hi) ^ swz) * 8)];
      }
#pragma unroll
      for (int j = 0; j < AN; j++) {
        int row = wn * (BN / WN) + j * 16 + l16;
        bfr[j] = *(const bf16x8*)&sB[row * BK + (((kk * 4 + hi) ^ swz) * 8)];
      }
#pragma unroll
      for (int i = 0; i < AM; i++)
#pragma unroll
        for (int j = 0; j < AN; j++)
          acc[i][j] = __builtin_amdgcn_mfma_f32_16x16x32_bf16(af[i], bfr[j], acc[i][j], 0, 0, 0);
    }
  }
}

// ---------------------------------------------------------------- QKV projections
// Grid (8, 32, 3). XCD = blockIdx.x. A-panel's 8 sharers pinned to one XCD.
__global__ __launch_bounds__(256, 3) void qkv_gemm(
    const unsigned short* qb, const unsigned short* kb, const unsigned short* vb,
    const unsigned short* wqb, const unsigned short* wkb, const unsigned short* wvb,
    const float* bq, const float* bk, const float* bv,
    unsigned short* Qp, unsigned short* Kp, unsigned short* Vt)
{
  const unsigned short* A; const unsigned short* B; const float* bias;
  if (blockIdx.z == 0)      { A = qb; B = wqb; bias = bq; }
  else if (blockIdx.z == 1) { A = kb; B = wkb; bias = bk; }
  else                      { A = vb; B = wvb; bias = bv; }

  const int xd = blockIdx.x, yd = blockIdx.y;
  const int mt = xd + 8 * (yd & 3);    // A-panel id 0..31, pinned to XCD xd
  const int nt = yd >> 2;              // 0..7
  const int tm = mt * 128, tn = nt * 128;

  f32x4 acc[4][4] = {};
  gemm_bt_main<128, 128, 2, 2>(A, B, acc, tm, tn);

  const int tid = threadIdx.x, wave = tid >> 6, lane = tid & 63;
  const int wm = wave >> 1, wn = wave & 1;
  const int l16 = lane & 15, hi = lane >> 4;

  if (blockIdx.z < 2) {
    unsigned short* C = (blockIdx.z == 0) ? Qp : Kp;
    const float scale = (blockIdx.z == 0) ? 0.18033688011112042f : 1.0f; // 0.125*log2(e)
#pragma unroll
    for (int i = 0; i < 4; i++) {
      int row0 = tm + wm * 64 + i * 16 + hi * 4;
#pragma unroll
      for (int j = 0; j < 4; j++) {
        int col = tn + wn * 64 + j * 16 + l16;
        float bv2 = bias[col];
#pragma unroll
        for (int r = 0; r < 4; r++)
          C[(size_t)(row0 + r) * 1024 + col] = f2bf((acc[i][j][r] + bv2) * scale);
      }
    }
  } else {
    // transposed V write: lane's 4 rows are 4 consecutive s -> one 8B store
#pragma unroll
    for (int i = 0; i < 4; i++) {
      int row0 = tm + wm * 64 + i * 16 + hi * 4;
      int bb = row0 >> 11, s = row0 & 2047;
#pragma unroll
      for (int j = 0; j < 4; j++) {
        int col = tn + wn * 64 + j * 16 + l16;
        int hh = col >> 6, d = col & 63;
        float bv2 = bias[col];
        u32x2 w;
        w[0] = cvtpk(acc[i][j][0] + bv2, acc[i][j][1] + bv2);
        w[1] = cvtpk(acc[i][j][2] + bv2, acc[i][j][3] + bv2);
        *(u32x2*)&Vt[((size_t)(bb * 16 + hh) * 64 + d) * 2048 + s] = w;
      }
    }
  }
}

// out-proj: 64x64 tiles -> grid (16,64) = 1024 blocks = 4 blocks/CU (was 2).
// XCD = (x + 16y)%8 = x%8; A-panel (mt) sharers all have same x&7 -> one XCD.
__global__ __launch_bounds__(256, 4) void out_gemm(
    const unsigned short* Yb, const unsigned short* wob, const float* bo, float* out)
{
  const int xd = blockIdx.x, yd = blockIdx.y;
  const int mt = (xd & 7) + 8 * (yd & 7);   // 0..63, pinned to XCD xd&7
  const int nt = (xd >> 3) + 2 * (yd >> 3); // 0..15
  const int tm = mt * 64, tn = nt * 64;

  f32x4 acc[1][4] = {};
  gemm_bt_main<64, 64, 4, 1>(Yb, wob, acc, tm, tn);

  const int tid = threadIdx.x, wave = tid >> 6, lane = tid & 63;
  const int l16 = lane & 15, hi = lane >> 4;
  int row0 = tm + wave * 16 + hi * 4;
#pragma unroll
  for (int j = 0; j < 4; j++) {
    int col = tn + j * 16 + l16;
    float bv2 = bo[col];
#pragma unroll
    for (int r = 0; r < 4; r++)
      out[(size_t)(row0 + r) * 1024 + col] = acc[0][j][r] + bv2;
  }
}

// ---------------------------------------------------------------- flash attention
// (r16 champion, verbatim) IN-BLOCK KV-SPLIT + SINGLE-BARRIER PIPELINE.
// 8 waves x 32 q-rows; waves 0-3 kv[0,1024), waves 4-7 kv[1024,2048), same 128 q.
// KVBLK=64 per half, double-buffered; one barrier per tile:
//   vmcnt(0) -> s_barrier -> issue stage(t+1) -> compute(t).
// Constant-max softmax (exp2(s-16), associative) -> halves combine via LDS.
__global__ __launch_bounds__(512, 2) void attn_kernel(
    const unsigned short* __restrict__ Qp, const unsigned short* __restrict__ Kp,
    const unsigned short* __restrict__ Vt, const int* __restrict__ mask,
    unsigned short* __restrict__ Yb)
{
  constexpr int S = 2048, H = 1024;
  __shared__ __align__(16) unsigned short smem[32768];   // 64KB

  const int tid = threadIdx.x, wave = tid >> 6, lane = tid & 63;
  const int l16 = lane & 15, hi = lane >> 4, swz = l16 & 7;
  const int half = wave >> 2, w4 = wave & 3;
  const int kvoff = half * 1024;
  const int xd = blockIdx.x, hd = blockIdx.y;
  const int h  = (xd & 7) + 8 * (hd & 1);            // pinned to XCD xd&7
  const int qt = ((xd >> 3) + 2 * (hd >> 1)) * 128;  // 0..15 q-tile
  const int b = blockIdx.z, bh = b * 16 + h;
  const unsigned short* Qb = Qp + (size_t)b * S * H + (size_t)h * 64;
  const unsigned short* Kb = Kp + (size_t)b * S * H + (size_t)h * 64;
  const unsigned short* Vb = Vt + (size_t)bh * 64 * 2048;

  unsigned short* sK0 = smem + (half * 2) * 4096;        // K buf0
  unsigned short* sK1 = smem + (half * 2 + 1) * 4096;    // K buf1
  unsigned short* sV0 = smem + 16384 + (half * 2) * 4096;
  unsigned short* sV1 = smem + 16384 + (half * 2 + 1) * 4096;

  // loop-invariant LDS read offsets (shorts; row stride 64)
  const int kinv0 = l16 * 64 + ((hi ^ swz) * 8);
  const int kinv1 = l16 * 64 + (((4 + hi) ^ swz) * 8);
  const int vinv0 = kinv0, vinv1 = kinv1;

  // ---- stage Q (128x64 = 16KB) into the two K1 bufs while K0/V0 prefetch
  {
    unsigned short* qdst0 = smem + 4096;    // rows 0..63
    unsigned short* qdst1 = smem + 12288;   // rows 64..127
#pragma unroll
    for (int i = 0; i < 2; i++) {
      int p = i * 512 + tid, row = p >> 3, c = p & 7;
      load_lds16(Qb + (size_t)(qt + row) * H + ((c ^ (row & 7)) * 8),
                 &(i ? qdst1 : qdst0)[(wave * 64) * 8]);
    }
  }
  // per-thread staging source pointers (advance by constants per tile)
  const int htid = tid & 255;
  const unsigned short* pK[2]; const unsigned short* pV[2];
#pragma unroll
  for (int j = 0; j < 2; j++) {
    int g = j * 256 + htid;
    int row = g >> 3, c = g & 7;
    pK[j] = Kb + (size_t)(kvoff + row) * H + ((c ^ (row & 7)) * 8);
    int d = g >> 3, kvc = g & 7;
    int sg = kvc ^ (d & 7);
    pV[j] = Vb + (size_t)d * 2048 + kvoff + sg * 8;
  }
#pragma unroll
  for (int j = 0; j < 2; j++)
    load_lds16(pK[j], &sK0[(j * 256 + w4 * 64) * 8]);
#pragma unroll
  for (int j = 0; j < 2; j++)
    load_lds16(pV[j], &sV0[(j * 256 + w4 * 64) * 8]);
#pragma unroll
  for (int j = 0; j < 2; j++) { pK[j] += 64 * H; pV[j] += 64; }

  asm volatile("s_waitcnt vmcnt(4)" ::: "memory");  // Q landed; K0/V0 still in flight
  __builtin_amdgcn_sched_barrier(0);
  __builtin_amdgcn_s_barrier();                     // all waves' Q visible

  bf16x8 qf[2][2];
#pragma unroll
  for (int m = 0; m < 2; m++) {
    const int row = w4 * 32 + m * 16 + l16;
    const int qm = mask[(size_t)b * S + qt + row];   // query-axis mask (matches ref)
    const unsigned short* qsrc = (row < 64) ? (smem + 4096 + row * 64)
                                            : (smem + 12288 + (row - 64) * 64);
#pragma unroll
    for (int ks = 0; ks < 2; ks++) {
      bf16x8 v = *(const bf16x8*)&qsrc[((ks * 4 + hi) ^ swz) * 8];
      u32x4 u = __builtin_bit_cast(u32x4, v);
#pragma unroll
      for (int c = 0; c < 4; c++) u[c] = qm ? u[c] : 0u;
      qf[m][ks] = __builtin_bit_cast(bf16x8, u);
    }
  }
  // Q-frag LDS reads must complete before any wave stages t=1 into the K1 bufs;
  // each wave drains its own reads here, the t=0 loop barrier globalizes it.
  asm volatile("s_waitcnt lgkmcnt(0)" ::: "memory");
  __builtin_amdgcn_sched_barrier(0);

  float lsum[2] = {0.f, 0.f};
  f32x4 oacc[2][4] = {};

  for (int t = 0; t < 16; t++) {
    const int cur = t & 1;
    // single-barrier pipeline point: stage(t) landed everywhere + compute(t-1)
    // finished everywhere (and at t=0: Q-frag reads done everywhere).
    asm volatile("s_waitcnt vmcnt(0)" ::: "memory");
    __builtin_amdgcn_sched_barrier(0);
    __builtin_amdgcn_s_barrier();

    // issue next-tile staging immediately; it lands during compute(t)
    if (t < 15) {
      unsigned short* nK = cur ? sK0 : sK1;
      unsigned short* nV = cur ? sV0 : sV1;
#pragma unroll
      for (int j = 0; j < 2; j++)
        load_lds16(pK[j], &nK[(j * 256 + w4 * 64) * 8]);
#pragma unroll
      for (int j = 0; j < 2; j++)
        load_lds16(pV[j], &nV[(j * 256 + w4 * 64) * 8]);
#pragma unroll
      for (int j = 0; j < 2; j++) { pK[j] += 64 * H; pV[j] += 64; }
    }

    const unsigned short* kb = cur ? sK1 : sK0;
    const unsigned short* vb = cur ? sV1 : sV0;

    // ---- QK^T swapped (64 kv): sf[m][jj] = S - 16 (log2 domain, C-init bake)
    f32x4 sf[2][4];
    __builtin_amdgcn_s_setprio(1);
#pragma unroll
    for (int jj = 0; jj < 4; jj++) {
      const int ro = jj * 1024;
      bf16x8 kf0 = *(const bf16x8*)&kb[ro + kinv0];
      bf16x8 kf1 = *(const bf16x8*)&kb[ro + kinv1];
#pragma unroll
      for (int m = 0; m < 2; m++) {
        f32x4 acc = {-16.0f, -16.0f, -16.0f, -16.0f};
        acc = __builtin_amdgcn_mfma_f32_16x16x32_bf16(kf0, qf[m][0], acc, 0, 0, 0);
        acc = __builtin_amdgcn_mfma_f32_16x16x32_bf16(kf1, qf[m][1], acc, 0, 0, 0);
        sf[m][jj] = acc;
      }
    }
    __builtin_amdgcn_s_setprio(0);

    // ---- constant-max softmax: P = exp2(s')
#pragma unroll
    for (int m = 0; m < 2; m++) {
#pragma unroll
      for (int jj = 0; jj < 4; jj++)
#pragma unroll
        for (int r = 0; r < 4; r++)
          sf[m][jj][r] = fexp2(sf[m][jj][r]);
      f32x4 c4 = (sf[m][0] + sf[m][1]) + (sf[m][2] + sf[m][3]);
      lsum[m] += (c4[0] + c4[1]) + (c4[2] + c4[3]);
    }

    // ---- P repack (permlane) + PV per 32-kv window; V-frag shared across m
#pragma unroll
    for (int w2 = 0; w2 < 2; w2++) {
      bf16x8 af0 = repack_af(sf[0][2 * w2], sf[0][2 * w2 + 1]);
      bf16x8 af1 = repack_af(sf[1][2 * w2], sf[1][2 * w2 + 1]);
      const int vo = w2 ? vinv1 : vinv0;
      __builtin_amdgcn_s_setprio(1);
#pragma unroll
      for (int n = 0; n < 4; n++) {
        bf16x8 vf = *(const bf16x8*)&vb[n * 1024 + vo];
        oacc[0][n] = __builtin_amdgcn_mfma_f32_16x16x32_bf16(af0, vf, oacc[0][n], 0, 0, 0);
        oacc[1][n] = __builtin_amdgcn_mfma_f32_16x16x32_bf16(af1, vf, oacc[1][n], 0, 0, 0);
      }
      __builtin_amdgcn_s_setprio(0);
    }
  }

  // ---- epilogue: reduce lsum across hi groups; combine halves via LDS
#pragma unroll
  for (int m = 0; m < 2; m++) {
    lsum[m] += __shfl_xor(lsum[m], 16);
    lsum[m] += __shfl_xor(lsum[m], 32);
  }

  __syncthreads();   // all waves done reading sK1/sV1 (t=15) before sO overwrite

  float* sO = (float*)smem;                 // [128][66] f32 = 33792B
  float* sL = (float*)(smem + 16896);       // 128 f32 (byte offset 33792)

  if (half == 1) {
#pragma unroll
    for (int m = 0; m < 2; m++) {
      if (hi == 0) sL[w4 * 32 + m * 16 + l16] = lsum[m];
#pragma unroll
      for (int n = 0; n < 4; n++)
#pragma unroll
        for (int r = 0; r < 4; r++) {
          int qq = w4 * 32 + m * 16 + hi * 4 + r;
          sO[qq * 66 + n * 16 + l16] = oacc[m][n][r];
        }
    }
  }
  __syncthreads();
  if (half == 0) {
#pragma unroll
    for (int m = 0; m < 2; m++) {
      float lt = lsum[m] + sL[w4 * 32 + m * 16 + l16];
      float lr[4];
#pragma unroll
      for (int r = 0; r < 4; r++) lr[r] = 1.0f / __shfl(lt, hi * 4 + r);
#pragma unroll
      for (int n = 0; n < 4; n++)
#pragma unroll
        for (int r = 0; r < 4; r++) {
          int qq = w4 * 32 + m * 16 + hi * 4 + r;
          int col = n * 16 + l16;
          float val = (oacc[m][n][r] + sO[qq * 66 + col]) * lr[r];
          Yb[((size_t)b * S + qt + qq) * H + h * 64 + col] = f2bf(val);
        }
    }
  }
}

// ---------------------------------------------------------------- launch
extern "C" void kernel_launch(void* const* d_in, const int* in_sizes, int n_in,
                              void* d_out, int out_size, void* d_ws, size_t ws_size,
                              hipStream_t stream)
{
  const float* q  = (const float*)d_in[0];
  const float* k  = (const float*)d_in[1];
  const float* v  = (const float*)d_in[2];
  const int*  mask = (const int*)d_in[3];
  const float* Wq = (const float*)d_in[4];
  const float* bq = (const float*)d_in[5];
  const float* Wk = (const float*)d_in[6];
  const float* bk = (const float*)d_in[7];
  const float* Wv = (const float*)d_in[8];
  const float* bv = (const float*)d_in[9];
  const float* Wo = (const float*)d_in[10];
  const float* bo = (const float*)d_in[11];

  unsigned short* ws  = (unsigned short*)d_ws;
  unsigned short* qb  = ws;                 //  0..4  EL
  unsigned short* kb  = ws + 4 * EL;        //  4..8
  unsigned short* vb  = ws + 8 * EL;        //  8..12
  unsigned short* wqb = ws + 12 * EL;       // 12..13
  unsigned short* wkb = ws + 13 * EL;       // 13..14
  unsigned short* wvb = ws + 14 * EL;       // 14..15
  unsigned short* wob = ws + 15 * EL;       // 15..16
  unsigned short* Qp  = ws + 16 * EL;       // 16..20
  unsigned short* Kp  = ws + 20 * EL;       // 20..24
  unsigned short* Vt  = ws + 24 * EL;       // 24..28  [32][64][2048] bf16
  unsigned short* Yb  = ws + 28 * EL;       // 28..32

  convert_all<<<2048, 256, 0, stream>>>(q, k, v, Wq, Wk, Wv, Wo, ws);
  qkv_gemm<<<dim3(8, 32, 3), 256, 0, stream>>>(qb, kb, vb, wqb, wkb, wvb,
                                               bq, bk, bv, Qp, Kp, Vt);
  attn_kernel<<<dim3(16, 16, 2), 512, 0, stream>>>(Qp, Kp, Vt, mask, Yb);
  out_gemm<<<dim3(16, 64), 256, 0, stream>>>(Yb, wob, bo, (float*)d_out);
}